// Round 4
// baseline (130.754 us; speedup 1.0000x reference)
//
#include <hip/hip_runtime.h>
#include <hip/hip_bf16.h>

#define LL 128
#define DD 256
#define PP 1024
#define TU_C 86400
#define TB_C 3600
#define NEGF -4294967296.0f   // float(-2**32+1) rounds to -2^32

// NOTE: parameter names must not collide with .x/.y/.z/.w member tokens
#define FMA4(ACC_, SS_, WW_) { (ACC_).x += (SS_)*(WW_).x; (ACC_).y += (SS_)*(WW_).y; (ACC_).z += (SS_)*(WW_).z; (ACC_).w += (SS_)*(WW_).w; }

__device__ __forceinline__ float wredSum(float v) {
#pragma unroll
  for (int o = 32; o; o >>= 1) v += __shfl_xor(v, o);
  return v;
}
__device__ __forceinline__ float wredMax(float v) {
#pragma unroll
  for (int o = 32; o; o >>= 1) v = fmaxf(v, __shfl_xor(v, o));
  return v;
}
__device__ __forceinline__ float dot4f(const float4 a, const float4 b) {
  return a.x * b.x + a.y * b.y + a.z * b.z + a.w * b.w;
}

// ---------------------------------------------------------------------------
// Kernel 0: transpose all weight matrices so GEMMs read coalesced.
// WT layout: WTq 0, WTk 65536, WTv 131072, WTf1 196608, WTf2 262144,
// WTdec 327680 (262144). 32x32 tiles, 576 blocks.
// ---------------------------------------------------------------------------
__global__ __launch_bounds__(256) void k_wt(
    const float* __restrict__ wq, const float* __restrict__ wk,
    const float* __restrict__ wv, const float* __restrict__ wf1,
    const float* __restrict__ wf2, const float* __restrict__ wdec,
    float* __restrict__ wt)
{
  __shared__ float s[32][33];
  const int tile = blockIdx.x;
  const float* src; float* dst; int R, m;
  if (tile < 320) {
    const int mi = tile >> 6; m = tile & 63;
    src = (mi == 0) ? wq : (mi == 1) ? wk : (mi == 2) ? wv : (mi == 3) ? wf1 : wf2;
    dst = wt + mi * 65536; R = 256;
  } else {
    m = tile - 320; src = wdec; dst = wt + 327680; R = 1024;
  }
  const int sr = (m >> 3) * 32, sc0 = (m & 7) * 32;
  const int tx = threadIdx.x & 31, ty = threadIdx.x >> 5;
#pragma unroll
  for (int i = 0; i < 4; ++i)
    s[ty + 8 * i][tx] = src[(sr + ty + 8 * i) * 256 + sc0 + tx];
  __syncthreads();
#pragma unroll
  for (int i = 0; i < 4; ++i)
    dst[(sc0 + ty + 8 * i) * R + sr + tx] = s[tx][ty + 8 * i];
}

// ---------------------------------------------------------------------------
// Kernel 1: Q/K/V projections. grid (64 row-tiles of 8, 3), 256 threads.
// K written TRANSPOSED per batch: KT[b][e][k].
// ---------------------------------------------------------------------------
__global__ __launch_bounds__(256) void k_qkv(
    const float* __restrict__ src, const float* __restrict__ wt,
    const float* __restrict__ bq, const float* __restrict__ bk,
    const float* __restrict__ bv,
    float* __restrict__ Q, float* __restrict__ KT, float* __restrict__ V)
{
  __shared__ float xs[8][DD];
  const int t = threadIdx.x, cg = t & 63, rg = t >> 6;
  const int r0 = blockIdx.x * 8;
  const int mat = blockIdx.y;
  const float* w = wt + mat * 65536;
  const float* bi = (mat == 0) ? bq : (mat == 1) ? bk : bv;
  for (int i = t; i < 8 * DD; i += 256) xs[i >> 8][i & 255] = src[r0 * DD + i];
  __syncthreads();
  const float4 bias4 = *(const float4*)(bi + 4 * cg);
  float4 a0 = bias4, a1 = bias4;
  const int rAl = 2 * rg, rBl = rAl + 1;
  for (int e = 0; e < DD; e += 4) {
    const float4 xa = *(const float4*)&xs[rAl][e];
    const float4 xb = *(const float4*)&xs[rBl][e];
    const float* wp = w + e * DD + 4 * cg;
    const float4 w0 = *(const float4*)(wp);
    const float4 w1 = *(const float4*)(wp + DD);
    const float4 w2 = *(const float4*)(wp + 2 * DD);
    const float4 w3 = *(const float4*)(wp + 3 * DD);
    FMA4(a0, xa.x, w0) FMA4(a0, xa.y, w1) FMA4(a0, xa.z, w2) FMA4(a0, xa.w, w3)
    FMA4(a1, xb.x, w0) FMA4(a1, xb.y, w1) FMA4(a1, xb.z, w2) FMA4(a1, xb.w, w3)
  }
  const int rA = r0 + rAl, rB = rA + 1;
  if (mat == 1) {
    const int bA = rA >> 7, kA = rA & 127;
    const float vA[4] = {a0.x, a0.y, a0.z, a0.w};
    const float vB[4] = {a1.x, a1.y, a1.z, a1.w};
#pragma unroll
    for (int c = 0; c < 4; ++c) {
      KT[bA * 32768 + (4 * cg + c) * 128 + kA]     = vA[c];
      KT[bA * 32768 + (4 * cg + c) * 128 + kA + 1] = vB[c];  // rA even -> same batch
    }
  } else {
    float* o = (mat == 0) ? Q : V;
    *(float4*)(o + rA * DD + 4 * cg) = a0;
    *(float4*)(o + rB * DD + 4 * cg) = a1;
  }
}

// ---------------------------------------------------------------------------
// Kernel 2: attention scores+softmax+weighted hist. grid 512=(b,j), 192 thr.
// Waves 0-1: K-dot via KT (coalesced). Wave 2: 34 embedding dots (parallel).
// Outputs: S[b*L+j][128] attention row, WH[b*L+j][34] weighted histograms.
// ---------------------------------------------------------------------------
__global__ __launch_bounds__(192) void k_attnA(
    const float* __restrict__ Q, const float* __restrict__ KT,
    const float* __restrict__ hour_emb, const float* __restrict__ day_emb,
    const int* __restrict__ seq_lens, const int* __restrict__ ts_g,
    float* __restrict__ Sout, float* __restrict__ WHout)
{
  const int b = blockIdx.x >> 7;
  const int j = blockIdx.x & (LL - 1);
  const int t = threadIdx.x;
  __shared__ float qrow[DD];
  __shared__ float qhd[34];
  __shared__ float whd[34];
  __shared__ float red[8];
  const int row = b * LL + j;
  for (int i = t; i < DD; i += 192) qrow[i] = Q[row * DD + i];
  if (t < 34) whd[t] = 0.f;
  __syncthreads();
  float kdot = 0.f;
  if (t < LL) {
    const float* ktb = KT + b * 32768;
#pragma unroll 8
    for (int e = 0; e < DD; e += 4) {
      const float4 q4 = *(const float4*)&qrow[e];
      const float* kp = ktb + e * LL + t;
      kdot += q4.x * kp[0] + q4.y * kp[128] + q4.z * kp[256] + q4.w * kp[384];
    }
  } else if (t < 162) {
    const int i = t - 128;
    const float* emb = (i < 26) ? (hour_emb + i * DD) : (day_emb + (i - 26) * DD);
    float a = 0.f;
    for (int e = 0; e < DD; e += 4)
      a += dot4f(*(const float4*)&qrow[e], *(const float4*)(emb + e));
    qhd[i] = a;
  }
  const int len = seq_lens[b];
  const int* ts = ts_g + b * LL;
  const int tj = ts[j];
  __syncthreads();  // qhd ready
  int hidx = 0, didx = 0;
  float s = NEGF;
  const bool valid = (t < LL) && (j < len) && (t <= j);
  if (valid) {
    const int diff = tj - ts[t];                       // >= 0 (ts sorted, t<=j)
    hidx = (j == b) ? 1 : ((diff % TU_C) / TB_C + 2);  // faithful j==b bug
    didx = min(diff / TU_C + 1, 7);
    s = (kdot + qhd[hidx] + qhd[26 + didx]) * 0.0625f; // /sqrt(256)
  }
  // softmax over k=0..127 (all-NEG rows -> uniform 1/128, like reference)
  float mv = (t < LL) ? s : -3.4e38f;
  mv = wredMax(mv);
  if ((t & 63) == 0) red[t >> 6] = mv;
  __syncthreads();
  const float m = fmaxf(red[0], red[1]);
  const float p = (t < LL) ? expf(s - m) : 0.f;
  const float sv = wredSum(p);
  if ((t & 63) == 0) red[4 + (t >> 6)] = sv;
  __syncthreads();
  const float Z = red[4] + red[5];
  if (t < LL) {
    const float aw = p / Z;
    Sout[row * LL + t] = aw;
    atomicAdd(&whd[hidx], aw);       // idx 0 -> zero embedding row: harmless
    atomicAdd(&whd[26 + didx], aw);
  }
  __syncthreads();
  if (t < 34) WHout[row * 34 + t] = whd[t];
}

// ---------------------------------------------------------------------------
// Kernel 3: fused (aw@V + hist@emb + residual + LN1) + FFN + LN2 -> F.
// grid 128 = (b, 32 row-tiles of 4), 256 threads. X never leaves LDS.
// ---------------------------------------------------------------------------
__global__ __launch_bounds__(256) void k_attnF(
    const float* __restrict__ Sin, const float* __restrict__ WHin,
    const float* __restrict__ Vm, const float* __restrict__ src,
    const float* __restrict__ hour_emb, const float* __restrict__ day_emb,
    const float* __restrict__ g11, const float* __restrict__ b11,
    const float* __restrict__ wt1, const float* __restrict__ bf1,
    const float* __restrict__ wt2, const float* __restrict__ bf2,
    const float* __restrict__ g12, const float* __restrict__ b12,
    float* __restrict__ F)
{
  const int b = blockIdx.x >> 5;
  const int r0 = (blockIdx.x & 31) * 4;     // local row base within batch
  const int t = threadIdx.x, cg = t & 63, rg = t >> 6;   // row rg of 4
  __shared__ float ss[4][LL];
  __shared__ float wh[4][34];
  __shared__ float xs[4][DD];
  __shared__ float hs[4][DD];
  const int gbase = b * LL + r0;
  for (int i = t; i < 4 * LL; i += 256) ss[i >> 7][i & 127] = Sin[gbase * LL + i];
  if (t < 136) wh[t / 34][t % 34] = WHin[gbase * 34 + t];
  __syncthreads();
  // ---- x = aw@V + whd@emb + src, LN1 ----
  float4 a = {0.f, 0.f, 0.f, 0.f};
  const float* vb = Vm + b * LL * DD + 4 * cg;
#pragma unroll 4
  for (int k = 0; k < LL; ++k) {
    const float4 v4 = *(const float4*)(vb + k * DD);
    FMA4(a, ss[rg][k], v4)
  }
#pragma unroll
  for (int i = 0; i < 26; ++i) {
    const float4 e4 = *(const float4*)(hour_emb + i * DD + 4 * cg);
    FMA4(a, wh[rg][i], e4)
  }
#pragma unroll
  for (int i = 0; i < 8; ++i) {
    const float4 e4 = *(const float4*)(day_emb + i * DD + 4 * cg);
    FMA4(a, wh[rg][26 + i], e4)
  }
  const float4 sr4 = *(const float4*)(src + (gbase + rg) * DD + 4 * cg);
  a.x += sr4.x; a.y += sr4.y; a.z += sr4.z; a.w += sr4.w;
  // LN1 (wave rg holds row rg's 256 cols)
  {
    const float sm = wredSum(a.x + a.y + a.z + a.w);
    const float sq = wredSum(a.x * a.x + a.y * a.y + a.z * a.z + a.w * a.w);
    const float mean = sm * (1.f / DD);
    const float rstd = rsqrtf(sq * (1.f / DD) - mean * mean + 1e-5f);
    const float4 g4 = *(const float4*)(g11 + 4 * cg);
    const float4 b4 = *(const float4*)(b11 + 4 * cg);
    a.x = (a.x - mean) * rstd * g4.x + b4.x;
    a.y = (a.y - mean) * rstd * g4.y + b4.y;
    a.z = (a.z - mean) * rstd * g4.z + b4.z;
    a.w = (a.w - mean) * rstd * g4.w + b4.w;
  }
  *(float4*)&xs[rg][4 * cg] = a;
  __syncthreads();
  // ---- H = relu(x @ W1^T + b1) ----
  float4 h = *(const float4*)(bf1 + 4 * cg);
  for (int e = 0; e < DD; e += 4) {
    const float4 xa = *(const float4*)&xs[rg][e];
    const float* wp = wt1 + e * DD + 4 * cg;
    const float4 w0 = *(const float4*)(wp);
    const float4 w1 = *(const float4*)(wp + DD);
    const float4 w2 = *(const float4*)(wp + 2 * DD);
    const float4 w3 = *(const float4*)(wp + 3 * DD);
    FMA4(h, xa.x, w0) FMA4(h, xa.y, w1) FMA4(h, xa.z, w2) FMA4(h, xa.w, w3)
  }
  h.x = fmaxf(h.x, 0.f); h.y = fmaxf(h.y, 0.f);
  h.z = fmaxf(h.z, 0.f); h.w = fmaxf(h.w, 0.f);
  *(float4*)&hs[rg][4 * cg] = h;
  __syncthreads();
  // ---- F = LN2(H @ W2^T + b2 + x) ----
  float4 o = *(const float4*)(bf2 + 4 * cg);
  for (int e = 0; e < DD; e += 4) {
    const float4 xa = *(const float4*)&hs[rg][e];
    const float* wp = wt2 + e * DD + 4 * cg;
    const float4 w0 = *(const float4*)(wp);
    const float4 w1 = *(const float4*)(wp + DD);
    const float4 w2 = *(const float4*)(wp + 2 * DD);
    const float4 w3 = *(const float4*)(wp + 3 * DD);
    FMA4(o, xa.x, w0) FMA4(o, xa.y, w1) FMA4(o, xa.z, w2) FMA4(o, xa.w, w3)
  }
  const float4 xr = *(const float4*)&xs[rg][4 * cg];
  o.x += xr.x; o.y += xr.y; o.z += xr.z; o.w += xr.w;
  {
    const float sm = wredSum(o.x + o.y + o.z + o.w);
    const float sq = wredSum(o.x * o.x + o.y * o.y + o.z * o.z + o.w * o.w);
    const float mean = sm * (1.f / DD);
    const float rstd = rsqrtf(sq * (1.f / DD) - mean * mean + 1e-5f);
    const float4 g4 = *(const float4*)(g12 + 4 * cg);
    const float4 b4 = *(const float4*)(b12 + 4 * cg);
    o.x = (o.x - mean) * rstd * g4.x + b4.x;
    o.y = (o.y - mean) * rstd * g4.y + b4.y;
    o.z = (o.z - mean) * rstd * g4.z + b4.z;
    o.w = (o.w - mean) * rstd * g4.w + b4.w;
  }
  *(float4*)(F + (gbase + rg) * DD + 4 * cg) = o;
}

// ---------------------------------------------------------------------------
// Kernel 4: GS rows via shared prefix scan + label-hist. grid 32 = (b, 8
// j-groups of 16), 256 threads (= d). Embedding columns live in registers.
// ---------------------------------------------------------------------------
__global__ __launch_bounds__(256) void k_prep(
    const float* __restrict__ F,
    const float* __restrict__ hour_emb, const float* __restrict__ day_emb,
    const int* __restrict__ seq_lens, const int* __restrict__ ts_g,
    const int* __restrict__ lts_g,
    float* __restrict__ GS)
{
  const int b = blockIdx.x >> 3;
  const int j0 = (blockIdx.x & 7) * 16;
  const int t = threadIdx.x;
  __shared__ float cnt[16][34];
  for (int i = t; i < 16 * 34; i += 256) (&cnt[0][0])[i] = 0.f;
  __syncthreads();
  const int len = seq_lens[b];
  const int* ts = ts_g + b * LL;
  const int* lts = lts_g + b * LL;
#pragma unroll
  for (int pass = 0; pass < 8; ++pass) {
    const int jj = pass * 2 + (t >> 7);
    const int k = t & 127;
    const int j = j0 + jj;
    if (k <= j && j < len) {          // valid; no j==b override for labels
      const int ldiff = lts[j] - ts[k];   // >= 0
      atomicAdd(&cnt[jj][(ldiff % TU_C) / TB_C + 2], 1.f);
      atomicAdd(&cnt[jj][26 + min(ldiff / TU_C + 1, 7)], 1.f);
    }
  }
  __syncthreads();
  float he[26], de[8];
#pragma unroll
  for (int i = 0; i < 26; ++i) he[i] = hour_emb[i * DD + t];
#pragma unroll
  for (int i = 0; i < 8; ++i)  de[i] = day_emb[i * DD + t];
  float gacc = 0.f;
  const float* fb = F + b * LL * DD;
  const int kend = j0 + 16;
  for (int k = 0; k < kend; ++k) {
    gacc += fb[k * DD + t];           // pooling sums ALL k<=j
    if (k >= j0) {
      const int jj = k - j0;
      float sv = 0.f;
#pragma unroll
      for (int i = 0; i < 26; ++i) sv += cnt[jj][i] * he[i];
#pragma unroll
      for (int i = 0; i < 8; ++i)  sv += cnt[jj][26 + i] * de[i];
      GS[(b * LL + k) * DD + t] = (gacc + sv) / (float)(k + 1);
    }
  }
}

// ---------------------------------------------------------------------------
// Kernel 5: decoder GEMM pooled = GS @ WTdec + bdec.
// grid (8 col-tiles of 128, 32 row-tiles of 16), 256 thr, 2 rows x 4 cols/thr.
// ---------------------------------------------------------------------------
__global__ __launch_bounds__(256) void k_dec(
    const float* __restrict__ GS, const float* __restrict__ wtd,
    const float* __restrict__ bdec, float* __restrict__ out)
{
  __shared__ float xs[16][DD];
  const int t = threadIdx.x;
  const int c0 = blockIdx.x * 128;
  const int r0 = blockIdx.y * 16;
  for (int i = t; i < 16 * DD; i += 256) xs[i >> 8][i & 255] = GS[r0 * DD + i];
  __syncthreads();
  const int cq = t & 31, rg = t >> 5;
  const int col = c0 + 4 * cq;
  const int rA = 2 * rg, rB = rA + 1;
  const float4 b4 = *(const float4*)(bdec + col);
  float4 a0 = b4, a1 = b4;
#pragma unroll 4
  for (int e = 0; e < DD; ++e) {
    const float4 w4 = *(const float4*)(wtd + e * PP + col);
    FMA4(a0, xs[rA][e], w4)
    FMA4(a1, xs[rB][e], w4)
  }
  *(float4*)(out + (r0 + rA) * PP + col) = a0;
  *(float4*)(out + (r0 + rB) * PP + col) = a1;
}

extern "C" void kernel_launch(void* const* d_in, const int* in_sizes, int n_in,
                              void* d_out, int out_size, void* d_ws, size_t ws_size,
                              hipStream_t stream)
{
  (void)in_sizes; (void)n_in; (void)out_size; (void)ws_size;
  const float* src      = (const float*)d_in[0];
  const float* hour_emb = (const float*)d_in[1];
  const float* day_emb  = (const float*)d_in[2];
  const float* wq  = (const float*)d_in[3];
  const float* bq  = (const float*)d_in[4];
  const float* wk  = (const float*)d_in[5];
  const float* bk  = (const float*)d_in[6];
  const float* wv  = (const float*)d_in[7];
  const float* bv  = (const float*)d_in[8];
  const float* g11 = (const float*)d_in[9];
  const float* b11 = (const float*)d_in[10];
  const float* wf1 = (const float*)d_in[11];
  const float* bf1 = (const float*)d_in[12];
  const float* wf2 = (const float*)d_in[13];
  const float* bf2 = (const float*)d_in[14];
  const float* g12 = (const float*)d_in[15];
  const float* b12 = (const float*)d_in[16];
  const float* wdec = (const float*)d_in[17];
  const float* bdec = (const float*)d_in[18];
  const int* seq_lens = (const int*)d_in[19];
  const int* ts  = (const int*)d_in[20];
  const int* lts = (const int*)d_in[21];
  float* out = (float*)d_out;
  float* ws = (float*)d_ws;
  // ws layout (floats):
  float* WT  = ws;                  // 589824 (5x65536 + 262144)
  float* Q   = ws + 589824;         // 131072
  float* KT  = ws + 720896;         // 131072 (4 x [256e][128k])
  float* V   = ws + 851968;         // 131072
  float* F   = ws + 983040;         // 131072
  float* GS  = ws + 1114112;        // 131072
  float* S   = ws + 1245184;        // 65536  (512 x 128 attention rows)
  float* WH  = ws + 1310720;        // 17408  (512 x 34 weighted hists)

  k_wt   <<<576, 256, 0, stream>>>(wq, wk, wv, wf1, wf2, wdec, WT);
  k_qkv  <<<dim3(64, 3), 256, 0, stream>>>(src, WT, bq, bk, bv, Q, KT, V);
  k_attnA<<<512, 192, 0, stream>>>(Q, KT, hour_emb, day_emb, seq_lens, ts, S, WH);
  k_attnF<<<128, 256, 0, stream>>>(S, WH, V, src, hour_emb, day_emb, g11, b11,
                                   WT + 196608, bf1, WT + 262144, bf2, g12, b12, F);
  k_prep <<<32, 256, 0, stream>>>(F, hour_emb, day_emb, seq_lens, ts, lts, GS);
  k_dec  <<<dim3(8, 32), 256, 0, stream>>>(GS, WT + 327680, bdec, out);
}

// Round 7
// 79.765 us; speedup vs baseline: 1.6392x; 1.6392x over previous
//
#include <hip/hip_runtime.h>
#include <hip/hip_bf16.h>

#define LL 128
#define DD 256
#define PP 1024
#define TU_C 86400
#define TB_C 3600
#define NEGF -4294967296.0f   // float(-2**32+1) rounds to -2^32

// NOTE: parameter names must not collide with .x/.y/.z/.w member tokens
#define FMA4(ACC_, SS_, WW_) { (ACC_).x += (SS_)*(WW_).x; (ACC_).y += (SS_)*(WW_).y; (ACC_).z += (SS_)*(WW_).z; (ACC_).w += (SS_)*(WW_).w; }

__device__ __forceinline__ float wredSum(float v) {
#pragma unroll
  for (int o = 32; o; o >>= 1) v += __shfl_xor(v, o);
  return v;
}
__device__ __forceinline__ float wredMax(float v) {
#pragma unroll
  for (int o = 32; o; o >>= 1) v = fmaxf(v, __shfl_xor(v, o));
  return v;
}
__device__ __forceinline__ float dot4f(const float4 a, const float4 b) {
  return a.x * b.x + a.y * b.y + a.z * b.z + a.w * b.w;
}

// ---------------------------------------------------------------------------
// Kernel 0: transpose all weight matrices so GEMMs read coalesced.
// WT layout: WTq 0, WTk 65536, WTv 131072, WTf1 196608, WTf2 262144,
// WTdec 327680 (262144). 32x32 tiles, 576 blocks.
// ---------------------------------------------------------------------------
__global__ __launch_bounds__(256) void k_wt(
    const float* __restrict__ wq, const float* __restrict__ wk,
    const float* __restrict__ wv, const float* __restrict__ wf1,
    const float* __restrict__ wf2, const float* __restrict__ wdec,
    float* __restrict__ wt)
{
  __shared__ float s[32][33];
  const int tile = blockIdx.x;
  const float* src; float* dst; int R, m;
  if (tile < 320) {
    const int mi = tile >> 6; m = tile & 63;
    src = (mi == 0) ? wq : (mi == 1) ? wk : (mi == 2) ? wv : (mi == 3) ? wf1 : wf2;
    dst = wt + mi * 65536; R = 256;
  } else {
    m = tile - 320; src = wdec; dst = wt + 327680; R = 1024;
  }
  const int sr = (m >> 3) * 32, sc0 = (m & 7) * 32;
  const int tx = threadIdx.x & 31, ty = threadIdx.x >> 5;
#pragma unroll
  for (int i = 0; i < 4; ++i)
    s[ty + 8 * i][tx] = src[(sr + ty + 8 * i) * 256 + sc0 + tx];
  __syncthreads();
#pragma unroll
  for (int i = 0; i < 4; ++i)
    dst[(sc0 + ty + 8 * i) * R + sr + tx] = s[tx][ty + 8 * i];
}

// ---------------------------------------------------------------------------
// Kernel 1: Q/K/V projections. grid (64 row-tiles of 8, 3), 256 threads.
// K written TRANSPOSED per batch: KT[b][e][k].
// ---------------------------------------------------------------------------
__global__ __launch_bounds__(256) void k_qkv(
    const float* __restrict__ src, const float* __restrict__ wt,
    const float* __restrict__ bq, const float* __restrict__ bk,
    const float* __restrict__ bv,
    float* __restrict__ Q, float* __restrict__ KT, float* __restrict__ V)
{
  __shared__ float xs[8][DD];
  const int t = threadIdx.x, cg = t & 63, rg = t >> 6;
  const int r0 = blockIdx.x * 8;
  const int mat = blockIdx.y;
  const float* w = wt + mat * 65536;
  const float* bi = (mat == 0) ? bq : (mat == 1) ? bk : bv;
  for (int i = t; i < 8 * DD; i += 256) xs[i >> 8][i & 255] = src[r0 * DD + i];
  __syncthreads();
  const float4 bias4 = *(const float4*)(bi + 4 * cg);
  float4 a0 = bias4, a1 = bias4;
  const int rAl = 2 * rg, rBl = rAl + 1;
  for (int e = 0; e < DD; e += 4) {
    const float4 xa = *(const float4*)&xs[rAl][e];
    const float4 xb = *(const float4*)&xs[rBl][e];
    const float* wp = w + e * DD + 4 * cg;
    const float4 w0 = *(const float4*)(wp);
    const float4 w1 = *(const float4*)(wp + DD);
    const float4 w2 = *(const float4*)(wp + 2 * DD);
    const float4 w3 = *(const float4*)(wp + 3 * DD);
    FMA4(a0, xa.x, w0) FMA4(a0, xa.y, w1) FMA4(a0, xa.z, w2) FMA4(a0, xa.w, w3)
    FMA4(a1, xb.x, w0) FMA4(a1, xb.y, w1) FMA4(a1, xb.z, w2) FMA4(a1, xb.w, w3)
  }
  const int rA = r0 + rAl, rB = rA + 1;
  if (mat == 1) {
    const int bA = rA >> 7, kA = rA & 127;
    const float vA[4] = {a0.x, a0.y, a0.z, a0.w};
    const float vB[4] = {a1.x, a1.y, a1.z, a1.w};
#pragma unroll
    for (int c = 0; c < 4; ++c) {
      KT[bA * 32768 + (4 * cg + c) * 128 + kA]     = vA[c];
      KT[bA * 32768 + (4 * cg + c) * 128 + kA + 1] = vB[c];  // rA even -> same batch
    }
  } else {
    float* o = (mat == 0) ? Q : V;
    *(float4*)(o + rA * DD + 4 * cg) = a0;
    *(float4*)(o + rB * DD + 4 * cg) = a1;
  }
}

// ---------------------------------------------------------------------------
// Kernel 2: attention scores+softmax+weighted hist. grid 512=(b,j), 192 thr.
// Waves 0-1: K-dot via KT (coalesced). Wave 2: 34 embedding dots (parallel).
// ---------------------------------------------------------------------------
__global__ __launch_bounds__(192) void k_attnA(
    const float* __restrict__ Q, const float* __restrict__ KT,
    const float* __restrict__ hour_emb, const float* __restrict__ day_emb,
    const int* __restrict__ seq_lens, const int* __restrict__ ts_g,
    float* __restrict__ Sout, float* __restrict__ WHout)
{
  const int b = blockIdx.x >> 7;
  const int j = blockIdx.x & (LL - 1);
  const int t = threadIdx.x;
  __shared__ float qrow[DD];
  __shared__ float qhd[34];
  __shared__ float whd[34];
  __shared__ float red[8];
  const int row = b * LL + j;
  for (int i = t; i < DD; i += 192) qrow[i] = Q[row * DD + i];
  if (t < 34) whd[t] = 0.f;
  __syncthreads();
  float kdot = 0.f;
  if (t < LL) {
    const float* ktb = KT + b * 32768;
#pragma unroll 8
    for (int e = 0; e < DD; e += 4) {
      const float4 q4 = *(const float4*)&qrow[e];
      const float* kp = ktb + e * LL + t;
      kdot += q4.x * kp[0] + q4.y * kp[128] + q4.z * kp[256] + q4.w * kp[384];
    }
  } else if (t < 162) {
    const int i = t - 128;
    const float* emb = (i < 26) ? (hour_emb + i * DD) : (day_emb + (i - 26) * DD);
    float a = 0.f;
    for (int e = 0; e < DD; e += 4)
      a += dot4f(*(const float4*)&qrow[e], *(const float4*)(emb + e));
    qhd[i] = a;
  }
  const int len = seq_lens[b];
  const int* ts = ts_g + b * LL;
  const int tj = ts[j];
  __syncthreads();  // qhd ready
  int hidx = 0, didx = 0;
  float s = NEGF;
  const bool valid = (t < LL) && (j < len) && (t <= j);
  if (valid) {
    const int diff = tj - ts[t];                       // >= 0 (ts sorted, t<=j)
    hidx = (j == b) ? 1 : ((diff % TU_C) / TB_C + 2);  // faithful j==b bug
    didx = min(diff / TU_C + 1, 7);
    s = (kdot + qhd[hidx] + qhd[26 + didx]) * 0.0625f; // /sqrt(256)
  }
  // softmax over k=0..127 (all-NEG rows -> uniform 1/128, like reference)
  float mv = (t < LL) ? s : -3.4e38f;
  mv = wredMax(mv);
  if ((t & 63) == 0) red[t >> 6] = mv;
  __syncthreads();
  const float m = fmaxf(red[0], red[1]);
  const float p = (t < LL) ? expf(s - m) : 0.f;
  const float sv = wredSum(p);
  if ((t & 63) == 0) red[4 + (t >> 6)] = sv;
  __syncthreads();
  const float Z = red[4] + red[5];
  if (t < LL) {
    const float aw = p / Z;
    Sout[row * LL + t] = aw;
    atomicAdd(&whd[hidx], aw);       // idx 0 -> zero embedding row: harmless
    atomicAdd(&whd[26 + didx], aw);
  }
  __syncthreads();
  if (t < 34) WHout[row * 34 + t] = whd[t];
}

// ---------------------------------------------------------------------------
// Kernel 3: fused (aw@V + hist@emb + residual + LN1) + FFN + LN2 -> F.
// grid 256 = (b, 64 row-pairs), 256 threads = 4 waves.
// Each row handled by 2 waves (split-K / split-E) with LDS combine.
// ---------------------------------------------------------------------------
__global__ __launch_bounds__(256) void k_attnF(
    const float* __restrict__ Sin, const float* __restrict__ WHin,
    const float* __restrict__ Vm, const float* __restrict__ src,
    const float* __restrict__ hour_emb, const float* __restrict__ day_emb,
    const float* __restrict__ g11, const float* __restrict__ b11,
    const float* __restrict__ wt1, const float* __restrict__ bf1,
    const float* __restrict__ wt2, const float* __restrict__ bf2,
    const float* __restrict__ g12, const float* __restrict__ b12,
    float* __restrict__ F)
{
  const int b = blockIdx.x >> 6;
  const int r0 = (blockIdx.x & 63) * 2;
  const int t = threadIdx.x;
  const int w = t >> 6, lane = t & 63;
  const int r = w >> 1, h = w & 1;       // row 0/1 within pair, half 0/1
  const int col = 4 * lane;              // 4 cols per lane, 256 per wave
  __shared__ float ss[2][LL];
  __shared__ float wh[2][34];
  __shared__ float xs[2][DD];
  __shared__ float hs[2][DD];
  __shared__ float ps[4][DD];
  const int gbase = b * LL + r0;
  for (int i = t; i < 2 * LL; i += 256) ss[i >> 7][i & 127] = Sin[gbase * LL + i];
  if (t < 68) wh[t / 34][t % 34] = WHin[gbase * 34 + t];
  __syncthreads();
  // ---- Phase 1: partial x = aw@V (64 k's) + emb/src split ----
  float4 a = {0.f, 0.f, 0.f, 0.f};
  {
    const float* vb = Vm + b * LL * DD + col;
    const int k0 = h * 64;
#pragma unroll 8
    for (int k = k0; k < k0 + 64; ++k) {
      const float4 v4 = *(const float4*)(vb + k * DD);
      FMA4(a, ss[r][k], v4)
    }
    if (h == 0) {
#pragma unroll
      for (int i = 0; i < 26; ++i) {
        const float4 e4 = *(const float4*)(hour_emb + i * DD + col);
        FMA4(a, wh[r][i], e4)
      }
    } else {
#pragma unroll
      for (int i = 0; i < 8; ++i) {
        const float4 e4 = *(const float4*)(day_emb + i * DD + col);
        FMA4(a, wh[r][26 + i], e4)
      }
      const float4 sr4 = *(const float4*)(src + (gbase + r) * DD + col);
      a.x += sr4.x; a.y += sr4.y; a.z += sr4.z; a.w += sr4.w;
    }
  }
  *(float4*)&ps[w][col] = a;
  __syncthreads();
  if (h == 0) {   // wave 2r combines + LN1
    const float4 pa = *(const float4*)&ps[2 * r][col];
    const float4 pb = *(const float4*)&ps[2 * r + 1][col];
    float4 x;
    x.x = pa.x + pb.x; x.y = pa.y + pb.y; x.z = pa.z + pb.z; x.w = pa.w + pb.w;
    const float sm = wredSum(x.x + x.y + x.z + x.w);
    const float sq = wredSum(x.x * x.x + x.y * x.y + x.z * x.z + x.w * x.w);
    const float mean = sm * (1.f / DD);
    const float rstd = rsqrtf(sq * (1.f / DD) - mean * mean + 1e-5f);
    const float4 g4 = *(const float4*)(g11 + col);
    const float4 b4 = *(const float4*)(b11 + col);
    x.x = (x.x - mean) * rstd * g4.x + b4.x;
    x.y = (x.y - mean) * rstd * g4.y + b4.y;
    x.z = (x.z - mean) * rstd * g4.z + b4.z;
    x.w = (x.w - mean) * rstd * g4.w + b4.w;
    *(float4*)&xs[r][col] = x;
  }
  __syncthreads();
  // ---- Phase 2: H = relu(x @ W1^T + b1), e-range split ----
  float4 hacc = {0.f, 0.f, 0.f, 0.f};
  if (h == 0) hacc = *(const float4*)(bf1 + col);
  {
    const int e0 = h * 128;
    for (int e = e0; e < e0 + 128; e += 4) {
      const float4 xa = *(const float4*)&xs[r][e];
      const float* wp = wt1 + e * DD + col;
      const float4 w0 = *(const float4*)(wp);
      const float4 w1 = *(const float4*)(wp + DD);
      const float4 w2 = *(const float4*)(wp + 2 * DD);
      const float4 w3 = *(const float4*)(wp + 3 * DD);
      FMA4(hacc, xa.x, w0) FMA4(hacc, xa.y, w1) FMA4(hacc, xa.z, w2) FMA4(hacc, xa.w, w3)
    }
  }
  *(float4*)&ps[w][col] = hacc;
  __syncthreads();
  if (h == 1) {   // wave 2r+1 combines + relu
    const float4 pa = *(const float4*)&ps[2 * r][col];
    const float4 pb = *(const float4*)&ps[2 * r + 1][col];
    float4 hv;
    hv.x = fmaxf(pa.x + pb.x, 0.f); hv.y = fmaxf(pa.y + pb.y, 0.f);
    hv.z = fmaxf(pa.z + pb.z, 0.f); hv.w = fmaxf(pa.w + pb.w, 0.f);
    *(float4*)&hs[r][col] = hv;
  }
  __syncthreads();
  // ---- Phase 3: F = LN2(H @ W2^T + b2 + x), e-range split ----
  float4 o = {0.f, 0.f, 0.f, 0.f};
  if (h == 0) o = *(const float4*)(bf2 + col);
  {
    const int e0 = h * 128;
    for (int e = e0; e < e0 + 128; e += 4) {
      const float4 xa = *(const float4*)&hs[r][e];
      const float* wp = wt2 + e * DD + col;
      const float4 w0 = *(const float4*)(wp);
      const float4 w1 = *(const float4*)(wp + DD);
      const float4 w2 = *(const float4*)(wp + 2 * DD);
      const float4 w3 = *(const float4*)(wp + 3 * DD);
      FMA4(o, xa.x, w0) FMA4(o, xa.y, w1) FMA4(o, xa.z, w2) FMA4(o, xa.w, w3)
    }
  }
  *(float4*)&ps[w][col] = o;
  __syncthreads();
  if (h == 0) {   // wave 2r combines + residual + LN2
    const float4 pa = *(const float4*)&ps[2 * r][col];
    const float4 pb = *(const float4*)&ps[2 * r + 1][col];
    const float4 xr = *(const float4*)&xs[r][col];
    float4 x;
    x.x = pa.x + pb.x + xr.x; x.y = pa.y + pb.y + xr.y;
    x.z = pa.z + pb.z + xr.z; x.w = pa.w + pb.w + xr.w;
    const float sm = wredSum(x.x + x.y + x.z + x.w);
    const float sq = wredSum(x.x * x.x + x.y * x.y + x.z * x.z + x.w * x.w);
    const float mean = sm * (1.f / DD);
    const float rstd = rsqrtf(sq * (1.f / DD) - mean * mean + 1e-5f);
    const float4 g4 = *(const float4*)(g12 + col);
    const float4 b4 = *(const float4*)(b12 + col);
    x.x = (x.x - mean) * rstd * g4.x + b4.x;
    x.y = (x.y - mean) * rstd * g4.y + b4.y;
    x.z = (x.z - mean) * rstd * g4.z + b4.z;
    x.w = (x.w - mean) * rstd * g4.w + b4.w;
    *(float4*)(F + (gbase + r) * DD + col) = x;
  }
}

// ---------------------------------------------------------------------------
// Kernel 4a: 16-row tile sums of F. grid 32 = (b*8+m), 256 threads (d).
// ---------------------------------------------------------------------------
__global__ __launch_bounds__(256) void k_tsum(
    const float* __restrict__ F, float* __restrict__ TS)
{
  const int bm = blockIdx.x;           // (b*8+m); row base = bm*16
  const int t = threadIdx.x;
  const float* fb = F + bm * 16 * DD + t;
  float s = 0.f;
#pragma unroll
  for (int k = 0; k < 16; ++k) s += fb[k * DD];
  TS[bm * DD + t] = s;
}

// ---------------------------------------------------------------------------
// Kernel 4b: GS[b,j] = (tile-prefix + intra-tile rows + label-emb)/(j+1).
// grid 512 = (b,j), 256 threads (d). Histogram on 128 threads in parallel.
// ---------------------------------------------------------------------------
__global__ __launch_bounds__(256) void k_prep2(
    const float* __restrict__ F, const float* __restrict__ TS,
    const float* __restrict__ hour_emb, const float* __restrict__ day_emb,
    const int* __restrict__ seq_lens, const int* __restrict__ ts_g,
    const int* __restrict__ lts_g,
    float* __restrict__ GS)
{
  const int b = blockIdx.x >> 7;
  const int j = blockIdx.x & (LL - 1);
  const int t = threadIdx.x;
  __shared__ float cnt[34];
  if (t < 34) cnt[t] = 0.f;
  __syncthreads();
  const int len = seq_lens[b];
  if (t < LL && t <= j && j < len) {     // valid; no j==b override for labels
    const int ldiff = lts_g[b * LL + j] - ts_g[b * LL + t];   // >= 0
    atomicAdd(&cnt[(ldiff % TU_C) / TB_C + 2], 1.f);
    atomicAdd(&cnt[26 + min(ldiff / TU_C + 1, 7)], 1.f);
  }
  __syncthreads();
  const int mt = j >> 4, jr = j & 15;
  float gacc = 0.f;
  const float* tsb = TS + b * 8 * DD + t;
#pragma unroll
  for (int m = 0; m < 7; ++m) if (m < mt) gacc += tsb[m * DD];
  const float* fb = F + (b * LL + mt * 16) * DD + t;
  float rv[16];
#pragma unroll
  for (int kk = 0; kk < 16; ++kk) rv[kk] = fb[kk * DD];   // rows always in-bounds
#pragma unroll
  for (int kk = 0; kk < 16; ++kk) if (kk <= jr) gacc += rv[kk];
  float sv = 0.f;
#pragma unroll
  for (int i = 0; i < 26; ++i) sv += cnt[i] * hour_emb[i * DD + t];
#pragma unroll
  for (int i = 0; i < 8; ++i)  sv += cnt[26 + i] * day_emb[i * DD + t];
  GS[(b * LL + j) * DD + t] = (gacc + sv) / (float)(j + 1);
}

// ---------------------------------------------------------------------------
// Kernel 5: decoder GEMM pooled = GS @ WTdec + bdec.
// grid (4 col-tiles of 256, 64 row-tiles of 8), 256 thr. Wave = 2 rows x 256
// cols -> every weight load is a full 1KB coalesced line.
// ---------------------------------------------------------------------------
__global__ __launch_bounds__(256) void k_dec(
    const float* __restrict__ GS, const float* __restrict__ wtd,
    const float* __restrict__ bdec, float* __restrict__ out)
{
  __shared__ float xs[8][DD];
  const int t = threadIdx.x;
  const int c0 = blockIdx.x * 256;
  const int r0 = blockIdx.y * 8;
  for (int i = t; i < 8 * DD; i += 256) xs[i >> 8][i & 255] = GS[r0 * DD + i];
  __syncthreads();
  const int lane = t & 63, w = t >> 6;
  const int col = c0 + 4 * lane;
  const int rA = 2 * w, rB = rA + 1;
  const float4 b4 = *(const float4*)(bdec + col);
  float4 a0 = b4, a1 = b4;
#pragma unroll 8
  for (int e = 0; e < DD; ++e) {
    const float4 w4 = *(const float4*)(wtd + e * PP + col);
    FMA4(a0, xs[rA][e], w4)
    FMA4(a1, xs[rB][e], w4)
  }
  *(float4*)(out + (r0 + rA) * PP + col) = a0;
  *(float4*)(out + (r0 + rB) * PP + col) = a1;
}

extern "C" void kernel_launch(void* const* d_in, const int* in_sizes, int n_in,
                              void* d_out, int out_size, void* d_ws, size_t ws_size,
                              hipStream_t stream)
{
  (void)in_sizes; (void)n_in; (void)out_size; (void)ws_size;
  const float* src      = (const float*)d_in[0];
  const float* hour_emb = (const float*)d_in[1];
  const float* day_emb  = (const float*)d_in[2];
  const float* wq  = (const float*)d_in[3];
  const float* bq  = (const float*)d_in[4];
  const float* wk  = (const float*)d_in[5];
  const float* bk  = (const float*)d_in[6];
  const float* wv  = (const float*)d_in[7];
  const float* bv  = (const float*)d_in[8];
  const float* g11 = (const float*)d_in[9];
  const float* b11 = (const float*)d_in[10];
  const float* wf1 = (const float*)d_in[11];
  const float* bf1 = (const float*)d_in[12];
  const float* wf2 = (const float*)d_in[13];
  const float* bf2 = (const float*)d_in[14];
  const float* g12 = (const float*)d_in[15];
  const float* b12 = (const float*)d_in[16];
  const float* wdec = (const float*)d_in[17];
  const float* bdec = (const float*)d_in[18];
  const int* seq_lens = (const int*)d_in[19];
  const int* ts  = (const int*)d_in[20];
  const int* lts = (const int*)d_in[21];
  float* out = (float*)d_out;
  float* ws = (float*)d_ws;
  // ws layout (floats):
  float* WT  = ws;                  // 589824 (5x65536 + 262144)
  float* Q   = ws + 589824;         // 131072
  float* KT  = ws + 720896;         // 131072 (4 x [256e][128k])
  float* V   = ws + 851968;         // 131072
  float* F   = ws + 983040;         // 131072
  float* GS  = ws + 1114112;        // 131072
  float* S   = ws + 1245184;        // 65536  (512 x 128 attention rows)
  float* WH  = ws + 1310720;        // 17408  (512 x 34 weighted hists)
  float* TS  = ws + 1328128;        // 8192   (4 x 8 x 256 tile sums)

  k_wt   <<<576, 256, 0, stream>>>(wq, wk, wv, wf1, wf2, wdec, WT);
  k_qkv  <<<dim3(64, 3), 256, 0, stream>>>(src, WT, bq, bk, bv, Q, KT, V);
  k_attnA<<<512, 192, 0, stream>>>(Q, KT, hour_emb, day_emb, seq_lens, ts, S, WH);
  k_attnF<<<256, 256, 0, stream>>>(S, WH, V, src, hour_emb, day_emb, g11, b11,
                                   WT + 196608, bf1, WT + 262144, bf2, g12, b12, F);
  k_tsum <<<32, 256, 0, stream>>>(F, TS);
  k_prep2<<<512, 256, 0, stream>>>(F, TS, hour_emb, day_emb, seq_lens, ts, lts, GS);
  k_dec  <<<dim3(4, 64), 256, 0, stream>>>(GS, WT + 327680, bdec, out);
}